// Round 1
// baseline (237.634 us; speedup 1.0000x reference)
//
#include <hip/hip_runtime.h>

#define N_NODES 16384
#define FIN     256
#define FOUT    64
#define MAXNBR  1024   // binomial(16384, 0.002) mean~33; 1024 is >30 sigma safe

// ---------------- Kernel 1: support = x @ weight  [N,FIN]@[FIN,FOUT] ----------
__global__ __launch_bounds__(256) void support_gemm(
    const float* __restrict__ x, const float* __restrict__ w,
    float* __restrict__ support) {
  __shared__ float wl[FIN * FOUT];   // 64 KB: whole weight matrix
  __shared__ float xl[4][FIN];       // 4 KB: 4 rows of x
  const int t = threadIdx.x;

  // load weight: 16384 floats = 4096 float4, 256 threads -> 16 each (coalesced)
  const float4* w4 = (const float4*)w;
  float4* wl4 = (float4*)wl;
#pragma unroll
  for (int i = 0; i < 16; ++i) wl4[i * 256 + t] = w4[i * 256 + t];

  // load 4 rows of x: 1024 floats = 256 float4
  const int row0 = blockIdx.x * 4;
  const float4* x4 = (const float4*)(x + (size_t)row0 * FIN);
  ((float4*)xl)[t] = x4[t];
  __syncthreads();

  const int r = t >> 6;   // 0..3  (one wave per output row)
  const int c = t & 63;   // output column
  float acc = 0.f;
#pragma unroll 8
  for (int k = 0; k < FIN; ++k) acc += xl[r][k] * wl[k * FOUT + c];
  support[(size_t)(row0 + r) * FOUT + c] = acc;
}

// ---------------- Kernel 2: sparse mean-aggregate + bias ----------------------
// One block per adj row: stream 64KB row, compact nonzero cols, gather support.
__global__ __launch_bounds__(256) void aggregate(
    const float* __restrict__ adj, const float* __restrict__ support,
    const float* __restrict__ bias, float* __restrict__ out) {
  __shared__ int   nbr[MAXNBR];
  __shared__ int   cnt_s;
  __shared__ float sred[4][FOUT];
  __shared__ int   cred[4][FOUT];

  const int row = blockIdx.x;
  const int t   = threadIdx.x;
  if (t == 0) cnt_s = 0;
  __syncthreads();

  // Phase A: scan adj[row, :] with float4 loads (fully coalesced stream)
  const float4* a4 = (const float4*)(adj + (size_t)row * N_NODES);
#pragma unroll
  for (int v = 0; v < 16; ++v) {
    const int i4 = v * 256 + t;
    const float4 a = a4[i4];
    const int kbase = i4 * 4;
    if (a.x != 0.f) { int p = atomicAdd(&cnt_s, 1); if (p < MAXNBR) nbr[p] = kbase;     }
    if (a.y != 0.f) { int p = atomicAdd(&cnt_s, 1); if (p < MAXNBR) nbr[p] = kbase + 1; }
    if (a.z != 0.f) { int p = atomicAdd(&cnt_s, 1); if (p < MAXNBR) nbr[p] = kbase + 2; }
    if (a.w != 0.f) { int p = atomicAdd(&cnt_s, 1); if (p < MAXNBR) nbr[p] = kbase + 3; }
  }
  __syncthreads();
  const int m = min(cnt_s, MAXNBR);

  // Phase B: gather support rows. 4 groups x 64 cols; group g takes neighbors
  // g, g+4, g+8, ... Each wave reads 256B contiguous per neighbor (coalesced,
  // support is 4MB -> L2/LIC resident).
  const int c = t & 63, g = t >> 6;
  float s = 0.f; int cn = 0;
  for (int n = g; n < m; n += 4) {
    const float v = support[(size_t)nbr[n] * FOUT + c];
    s += v;
    cn += (v != 0.f) ? 1 : 0;
  }
  sred[g][c] = s; cred[g][c] = cn;
  __syncthreads();

  // Reduce 4 partials, fuse mean + bias
  if (t < FOUT) {
    const float st = sred[0][t] + sred[1][t] + sred[2][t] + sred[3][t];
    const int   ct = cred[0][t] + cred[1][t] + cred[2][t] + cred[3][t];
    out[(size_t)row * FOUT + t] = st / (float)ct + bias[t];
  }
}

extern "C" void kernel_launch(void* const* d_in, const int* in_sizes, int n_in,
                              void* d_out, int out_size, void* d_ws, size_t ws_size,
                              hipStream_t stream) {
  const float* x    = (const float*)d_in[0];
  const float* adj  = (const float*)d_in[1];
  const float* w    = (const float*)d_in[2];
  const float* bias = (const float*)d_in[3];
  float* out = (float*)d_out;
  float* support = (float*)d_ws;   // N_NODES * FOUT * 4 = 4 MB scratch

  support_gemm<<<N_NODES / 4, 256, 0, stream>>>(x, w, support);
  aggregate<<<N_NODES, 256, 0, stream>>>(adj, support, bias, out);
}

// Round 2
// 210.595 us; speedup vs baseline: 1.1284x; 1.1284x over previous
//
#include <hip/hip_runtime.h>

#define N_NODES 16384
#define FIN     256
#define FOUT    64
#define MAXNBR  1024   // mean ~33 neighbors; 1024 is >30 sigma headroom

typedef float f32x4 __attribute__((ext_vector_type(4)));

// ---------------- Kernel 1: support = x @ weight  [N,FIN]@[FIN,FOUT] ----------
__global__ __launch_bounds__(256) void support_gemm(
    const float* __restrict__ x, const float* __restrict__ w,
    float* __restrict__ support) {
  __shared__ float wl[FIN * FOUT];   // 64 KB: whole weight matrix
  __shared__ float xl[4][FIN];       // 4 KB: 4 rows of x
  const int t = threadIdx.x;

  const float4* w4 = (const float4*)w;
  float4* wl4 = (float4*)wl;
#pragma unroll
  for (int i = 0; i < 16; ++i) wl4[i * 256 + t] = w4[i * 256 + t];

  const int row0 = blockIdx.x * 4;
  const float4* x4 = (const float4*)(x + (size_t)row0 * FIN);
  ((float4*)xl)[t] = x4[t];
  __syncthreads();

  const int r = t >> 6;   // 0..3  (one wave per output row)
  const int c = t & 63;   // output column
  float acc = 0.f;
#pragma unroll 8
  for (int k = 0; k < FIN; ++k) acc += xl[r][k] * wl[k * FOUT + c];
  support[(size_t)(row0 + r) * FOUT + c] = acc;
}

// ---------------- Kernel 2: sparse mean-aggregate + bias ----------------------
// One block per adj row. Phase A: stream the 64KB row with 16 nontemporal
// float4 loads issued back-to-back (max MLP), then compact nonzero columns.
// Phase B: gather support rows (L2/L3-resident) + fused mean/bias epilogue.
__global__ __launch_bounds__(256) void aggregate(
    const float* __restrict__ adj, const float* __restrict__ support,
    const float* __restrict__ bias, float* __restrict__ out) {
  __shared__ int   nbr[MAXNBR];
  __shared__ int   cnt_s;
  __shared__ float sred[4][FOUT];
  __shared__ int   cred[4][FOUT];

  const int row = blockIdx.x;
  const int t   = threadIdx.x;
  if (t == 0) cnt_s = 0;
  __syncthreads();

  // Phase A1: issue ALL 16 loads first — no branches between them.
  const f32x4* a4 = (const f32x4*)(adj + (size_t)row * N_NODES);
  f32x4 av[16];
#pragma unroll
  for (int v = 0; v < 16; ++v) av[v] = __builtin_nontemporal_load(&a4[v * 256 + t]);

  // Phase A2: adj is binary {0,1}: quad-sum==0 <=> all four zero.
#pragma unroll
  for (int v = 0; v < 16; ++v) {
    const f32x4 a = av[v];
    const float qs = (a[0] + a[1]) + (a[2] + a[3]);
    if (qs != 0.f) {
      const int kbase = (v * 256 + t) * 4;
      if (a[0] != 0.f) { int p = atomicAdd(&cnt_s, 1); if (p < MAXNBR) nbr[p] = kbase;     }
      if (a[1] != 0.f) { int p = atomicAdd(&cnt_s, 1); if (p < MAXNBR) nbr[p] = kbase + 1; }
      if (a[2] != 0.f) { int p = atomicAdd(&cnt_s, 1); if (p < MAXNBR) nbr[p] = kbase + 2; }
      if (a[3] != 0.f) { int p = atomicAdd(&cnt_s, 1); if (p < MAXNBR) nbr[p] = kbase + 3; }
    }
  }
  __syncthreads();
  const int m = min(cnt_s, MAXNBR);

  // Phase B: gather support rows. Group g handles neighbors g, g+4, ...
  // Each wave reads 256B contiguous per neighbor (coalesced, cache-resident).
  const int c = t & 63, g = t >> 6;
  float s = 0.f; int cn = 0;
  for (int n = g; n < m; n += 4) {
    const float v = support[(size_t)nbr[n] * FOUT + c];
    s += v;
    cn += (v != 0.f) ? 1 : 0;
  }
  sred[g][c] = s; cred[g][c] = cn;
  __syncthreads();

  // Reduce 4 partials, fuse mean + bias
  if (t < FOUT) {
    const float st = sred[0][t] + sred[1][t] + sred[2][t] + sred[3][t];
    const int   ct = cred[0][t] + cred[1][t] + cred[2][t] + cred[3][t];
    out[(size_t)row * FOUT + t] = st / (float)ct + bias[t];
  }
}

extern "C" void kernel_launch(void* const* d_in, const int* in_sizes, int n_in,
                              void* d_out, int out_size, void* d_ws, size_t ws_size,
                              hipStream_t stream) {
  const float* x    = (const float*)d_in[0];
  const float* adj  = (const float*)d_in[1];
  const float* w    = (const float*)d_in[2];
  const float* bias = (const float*)d_in[3];
  float* out = (float*)d_out;
  float* support = (float*)d_ws;   // N_NODES * FOUT * 4 = 4 MB scratch

  support_gemm<<<N_NODES / 4, 256, 0, stream>>>(x, w, support);
  aggregate<<<N_NODES, 256, 0, stream>>>(adj, support, bias, out);
}

// Round 3
// 203.416 us; speedup vs baseline: 1.1682x; 1.0353x over previous
//
#include <hip/hip_runtime.h>

#define N_NODES 16384
#define FIN     256
#define FOUT    64
#define MAXW    512    // neighbor cap per row: mean ~32, sigma ~5.7 -> 84 sigma

typedef float f32x4 __attribute__((ext_vector_type(4)));

// ---------------- Kernel 1: support = x @ weight  [N,FIN]@[FIN,FOUT] ----------
// 16 rows/block, wave computes 4 rows. x read via ds_read_b128 broadcast,
// weight via 2-way-free b32 reads: ~0.5 ds_read per row per k (was 2).
__global__ __launch_bounds__(256) void support_gemm(
    const float* __restrict__ x, const float* __restrict__ w,
    float* __restrict__ support) {
  __shared__ float wl[FIN * FOUT];   // 64 KB  [k][c]
  __shared__ float xl[16][FIN];      // 16 KB  [r][k]
  const int t = threadIdx.x;

  const float4* w4 = (const float4*)w;
  float4* wl4 = (float4*)wl;
#pragma unroll
  for (int i = 0; i < 16; ++i) wl4[i * 256 + t] = w4[i * 256 + t];

  const int row0 = blockIdx.x * 16;
  const float4* x4 = (const float4*)(x + (size_t)row0 * FIN);
  float4* xl4 = (float4*)xl;
#pragma unroll
  for (int i = 0; i < 4; ++i) xl4[i * 256 + t] = x4[i * 256 + t];
  __syncthreads();

  const int wv = t >> 6;        // wave id 0..3
  const int c  = t & 63;        // output column
  const int r0 = wv * 4;        // this wave's 4 rows
  float acc0 = 0.f, acc1 = 0.f, acc2 = 0.f, acc3 = 0.f;

#pragma unroll 4
  for (int k = 0; k < FIN; k += 4) {
    const f32x4 xv0 = *(const f32x4*)&xl[r0 + 0][k];
    const f32x4 xv1 = *(const f32x4*)&xl[r0 + 1][k];
    const f32x4 xv2 = *(const f32x4*)&xl[r0 + 2][k];
    const f32x4 xv3 = *(const f32x4*)&xl[r0 + 3][k];
    const float w0 = wl[(k + 0) * FOUT + c];
    const float w1 = wl[(k + 1) * FOUT + c];
    const float w2 = wl[(k + 2) * FOUT + c];
    const float w3 = wl[(k + 3) * FOUT + c];
    acc0 += xv0[0] * w0 + xv0[1] * w1 + xv0[2] * w2 + xv0[3] * w3;
    acc1 += xv1[0] * w0 + xv1[1] * w1 + xv1[2] * w2 + xv1[3] * w3;
    acc2 += xv2[0] * w0 + xv2[1] * w1 + xv2[2] * w2 + xv2[3] * w3;
    acc3 += xv3[0] * w0 + xv3[1] * w1 + xv3[2] * w2 + xv3[3] * w3;
  }
  float* outp = support + (size_t)(row0 + r0) * FOUT + c;
  outp[0 * FOUT] = acc0;
  outp[1 * FOUT] = acc1;
  outp[2 * FOUT] = acc2;
  outp[3 * FOUT] = acc3;
}

// ---------------- Kernel 2: sparse mean-aggregate + bias ----------------------
// WAVE-per-row, barrier-free. Each wave: stream its 64KB adj row in 8 batches
// of 8 nontemporal float4 loads, compact nonzero cols into a private LDS slice
// (per-wave counter, no cross-wave traffic), then gather support rows with a
// 4-deep unrolled independent-load chain. No __syncthreads anywhere.
__global__ __launch_bounds__(256, 8) void aggregate(
    const float* __restrict__ adj, const float* __restrict__ support,
    const float* __restrict__ bias, float* __restrict__ out) {
  __shared__ int nbr[4][MAXW];
  __shared__ int cnt[4];

  const int t    = threadIdx.x;
  const int wv   = t >> 6;
  const int lane = t & 63;
  const int row  = blockIdx.x * 4 + wv;

  if (lane == 0) cnt[wv] = 0;   // wave-lockstep: ordered before the atomics

  // Phase A: stream adj row. 8 batches x 8 float4 loads, loads issued
  // back-to-back before any processing within a batch.
  const f32x4* a4 = (const f32x4*)(adj + (size_t)row * N_NODES);
#pragma unroll 1
  for (int h = 0; h < 8; ++h) {
    f32x4 av[8];
#pragma unroll
    for (int j = 0; j < 8; ++j)
      av[j] = __builtin_nontemporal_load(&a4[h * 512 + j * 64 + lane]);
#pragma unroll
    for (int j = 0; j < 8; ++j) {
      const f32x4 a = av[j];
      const int nz = (a[0] != 0.f) + (a[1] != 0.f) + (a[2] != 0.f) + (a[3] != 0.f);
      if (nz) {
        int p = atomicAdd(&cnt[wv], nz);
        if (p + nz <= MAXW) {
          const int kbase = (h * 512 + j * 64 + lane) * 4;
          if (a[0] != 0.f) nbr[wv][p++] = kbase;
          if (a[1] != 0.f) nbr[wv][p++] = kbase + 1;
          if (a[2] != 0.f) nbr[wv][p++] = kbase + 2;
          if (a[3] != 0.f) nbr[wv][p++] = kbase + 3;
        }
      }
    }
  }

  // Phase B: gather support rows (L2/L3-resident), 4 independent chains.
  const int m = min(cnt[wv], MAXW);
  float s0 = 0.f, s1 = 0.f, s2 = 0.f, s3 = 0.f;
  int   c0 = 0, c1 = 0, c2 = 0, c3 = 0;
  int n = 0;
  for (; n + 4 <= m; n += 4) {
    const float v0 = support[(size_t)nbr[wv][n + 0] * FOUT + lane];
    const float v1 = support[(size_t)nbr[wv][n + 1] * FOUT + lane];
    const float v2 = support[(size_t)nbr[wv][n + 2] * FOUT + lane];
    const float v3 = support[(size_t)nbr[wv][n + 3] * FOUT + lane];
    s0 += v0; c0 += (v0 != 0.f);
    s1 += v1; c1 += (v1 != 0.f);
    s2 += v2; c2 += (v2 != 0.f);
    s3 += v3; c3 += (v3 != 0.f);
  }
  for (; n < m; ++n) {
    const float v = support[(size_t)nbr[wv][n] * FOUT + lane];
    s0 += v; c0 += (v != 0.f);
  }
  const float s = (s0 + s1) + (s2 + s3);
  const int   c = (c0 + c1) + (c2 + c3);
  out[(size_t)row * FOUT + lane] = s / (float)c + bias[lane];
}

extern "C" void kernel_launch(void* const* d_in, const int* in_sizes, int n_in,
                              void* d_out, int out_size, void* d_ws, size_t ws_size,
                              hipStream_t stream) {
  const float* x    = (const float*)d_in[0];
  const float* adj  = (const float*)d_in[1];
  const float* w    = (const float*)d_in[2];
  const float* bias = (const float*)d_in[3];
  float* out = (float*)d_out;
  float* support = (float*)d_ws;   // 4 MB scratch

  support_gemm<<<N_NODES / 16, 256, 0, stream>>>(x, w, support);
  aggregate<<<N_NODES / 4, 256, 0, stream>>>(adj, support, bias, out);
}